// Round 1
// baseline (415.540 us; speedup 1.0000x reference)
//
#include <hip/hip_runtime.h>
#include <hip/hip_bf16.h>
#include <cstdint>

// ---------------- problem constants ----------------
#define NN      8192      // nodes
#define OF      64        // out features
#define NSLAB   4         // partial-sum slabs (was 16)
#define CPB     4         // K-chunks per k3 block (reg-accumulated)
#define CW      512       // K width per chunk (elements)
#define ASTR    72        // A LDS tile stride (shorts)
#define PSTR    65        // P slab row stride (floats): 64 cols + S

// ---------------- ws layout (bytes) ----------------
#define OFF_HW  0                           // HW 80x8192 u16       = 1310720
#define OFF_P   1310720                     // P 4x8192x65 f32      = 8519680

typedef __attribute__((ext_vector_type(8))) short  s16x8;
typedef __attribute__((ext_vector_type(4))) float  f32x4;

__device__ __forceinline__ unsigned short f2bf(float f) {
  unsigned int u = __float_as_uint(f);
  unsigned int r = (u + 0x7FFFu + ((u >> 16) & 1u)) >> 16;   // RNE
  return (unsigned short)r;
}

// ---------------- k1: h = X @ W (LDS-tiled fp32) -> fused e/HW write -------
__global__ __launch_bounds__(256) void k1_hw(const float* __restrict__ X,
                                             const float* __restrict__ W,
                                             const float* __restrict__ att,
                                             unsigned short* __restrict__ HW) {
  __shared__ float xs[16 * 516];
  __shared__ float ws[64 * 68];
  int t = threadIdx.x;
  int rb = blockIdx.x * 16;

  {
    const float4* src = (const float4*)(X + (size_t)rb * 512);
#pragma unroll
    for (int s = 0; s < 8; ++s) {
      int lid = s * 256 + t;
      int row = lid >> 7, kseg = lid & 127;
      *(float4*)&xs[row * 516 + kseg * 4] = src[row * 128 + kseg];
    }
  }

  int row = t >> 4, tx = t & 15;
  float4 acc = {0.f, 0.f, 0.f, 0.f};
  for (int kc = 0; kc < 8; ++kc) {
    __syncthreads();
#pragma unroll
    for (int s = 0; s < 4; ++s) {
      int lid = s * 256 + t;
      int k = lid >> 4, cs = lid & 15;
      *(float4*)&ws[k * 68 + cs * 4] =
          *(const float4*)(W + (size_t)(kc * 64 + k) * 64 + cs * 4);
    }
    __syncthreads();
#pragma unroll 16
    for (int k = 0; k < 64; ++k) {
      float x = xs[row * 516 + kc * 64 + k];
      float4 w4 = *(const float4*)&ws[k * 68 + tx * 4];
      acc.x += x * w4.x; acc.y += x * w4.y;
      acc.z += x * w4.z; acc.w += x * w4.w;
    }
  }

  float v = acc.x * att[64 + tx * 4]     + acc.y * att[64 + tx * 4 + 1] +
            acc.z * att[64 + tx * 4 + 2] + acc.w * att[64 + tx * 4 + 3];
#pragma unroll
  for (int m = 8; m > 0; m >>= 1) v += __shfl_xor(v, m, 64);
  float e = expf(v);                 // |r| <~ 21, no overflow

  int j = rb + row;
  unsigned short* hw = HW + j;
  float hv[4] = {acc.x, acc.y, acc.z, acc.w};
#pragma unroll
  for (int c = 0; c < 4; ++c)
    hw[(size_t)(tx * 4 + c) * NN] = f2bf(e * hv[c]);
  if (tx == 0) hw[(size_t)64 * NN] = f2bf(e);   // rows 65..79 never read
}

// ---------------- k3: 4 K-chunks per block, register-accumulated ----------
// Same per-chunk structure as the 16-slab version (full-depth 32-deep A
// dwordx4 burst -> swizzled resident B stage -> one barrier -> pure
// LDS+VALU+MFMA compute), but looped over CPB=4 chunks with acc[] carried
// in registers across chunks. Grid 128x4 = 512 blocks = still exactly
// 2 blocks/CU (75.7 KB LDS), so co-resident-block overlap of the A burst
// with the other block's compute is preserved. P shrinks 34MB -> 8.5MB.
__global__ __launch_bounds__(256, 2) void k3_gat(const int* __restrict__ A,
                                                 const unsigned short* __restrict__ HW,
                                                 float* __restrict__ P) {
  __shared__ unsigned short bt[65 * 512];   // 66560 B, XOR-swizzled B
  __shared__ unsigned short at[64 * ASTR];  //  9216 B, per-wave A regions

  int t = threadIdx.x;
  int sg = blockIdx.x & 3;                  // slab id; XCD-affine K-quarter
  int mg = blockIdx.x >> 2;                 // 0..127
  int lane = t & 63, w = t >> 6;
  int l15 = lane & 15, q = lane >> 4;
  int rowM = mg * 64;

  // A row pointers (column base added per chunk): instr i covers rows
  // w*16+i*4+q, 16 lanes x 16B contiguous
  const int* arow[4];
#pragma unroll
  for (int i = 0; i < 4; ++i)
    arow[i] = A + (size_t)(rowM + w * 16 + i * 4 + q) * NN + l15 * 4;

  // B ds_read byte-address bases (round-8-verified conflict-free)
  int swz = l15 & 7;
  int bb[4][2];
#pragma unroll
  for (int tt = 0; tt < 4; ++tt)
#pragma unroll
    for (int ks = 0; ks < 2; ++ks)
      bb[tt][ks] = ((tt * 16 + l15) * 512 + (((ks * 4 + q) ^ swz) * 8)) * 2;
  int eb0 = (64 * 512 + q * 8) * 2;
  int eb1 = (64 * 512 + (4 + q) * 8) * 2;
  int ab  = ((w * 16 + l15) * ASTR + q * 8) * 2;

  f32x4 acc[5];
#pragma unroll
  for (int tt = 0; tt < 5; ++tt) acc[tt] = 0.f;
  const s16x8 zero8 = {0, 0, 0, 0, 0, 0, 0, 0};

#pragma unroll 1
  for (int c = 0; c < CPB; ++c) {
    int k0 = (sg * CPB + c) * CW;

    // full-depth A preload: all 8 steps x 4 row-groups, one 32-deep burst
    int4 av[8][4];
#pragma unroll
    for (int s = 0; s < 8; ++s)
#pragma unroll
      for (int i = 0; i < 4; ++i)
        av[s][i] = *(const int4*)(arow[i] + k0 + s * 64);

    // stage B swizzled: chunk ch of row goes to position ch ^ (row & 7)
#pragma unroll
    for (int rds = 0; rds < 16; ++rds) {
      int lid = rds * 256 + t;
      int row = lid >> 6, ch = lid & 63;
      uint4 v = *(const uint4*)(HW + (size_t)row * NN + k0 + ch * 8);
      *(uint4*)&bt[row * 512 + ((ch ^ (row & 7)) * 8)] = v;
    }
    if (t < 64) {                           // row 64 (e-row), unswizzled
      uint4 v = *(const uint4*)(HW + (size_t)64 * NN + k0 + t * 8);
      *(uint4*)&bt[64 * 512 + t * 8] = v;
    }
    __syncthreads();                        // B(c) ready

#pragma unroll
    for (int s = 0; s < 8; ++s) {
      // write A(s) -> wave-private tile region (cvt int{0,1} -> packed bf16)
#pragma unroll
      for (int i = 0; i < 4; ++i) {
        int4 vv = av[s][i];
        uint2 p;
        p.x = (unsigned)(vv.x | (vv.y << 16)) * 0x3F80u;
        p.y = (unsigned)(vv.z | (vv.w << 16)) * 0x3F80u;
        *(uint2*)((char*)at + (((w * 16 + i * 4 + q) * ASTR + l15 * 4) * 2)) = p;
      }

      // wave-local read-back (lgkmcnt ordering only; no s_barrier)
      s16x8 af0 = *(const s16x8*)((char*)at + ab);
      s16x8 af1 = *(const s16x8*)((char*)at + ab + 64);
      int so = s * 128;                     // step byte offset within B row
#pragma unroll
      for (int ks = 0; ks < 2; ++ks) {
        s16x8 af = ks ? af1 : af0;
#pragma unroll
        for (int tt = 0; tt < 4; ++tt) {
          s16x8 b = *(const s16x8*)((char*)bt + bb[tt][ks] + so);
          acc[tt] = __builtin_amdgcn_mfma_f32_16x16x32_bf16(af, b, acc[tt], 0, 0, 0);
        }
        s16x8 b4 = *(const s16x8*)((char*)bt + (ks ? eb1 : eb0) + so);
        b4 = (l15 == 0) ? b4 : zero8;
        acc[4] = __builtin_amdgcn_mfma_f32_16x16x32_bf16(af, b4, acc[4], 0, 0, 0);
      }
    }
    __syncthreads();                        // B tile free for next stage
  }

  // epilogue: C/D layout col=l15, row=q*4+rg
  float* Pp = P + (size_t)sg * NN * PSTR;
  int rb = rowM + w * 16 + q * 4;
#pragma unroll
  for (int tt = 0; tt < 4; ++tt)
#pragma unroll
    for (int rg = 0; rg < 4; ++rg)
      Pp[(size_t)(rb + rg) * PSTR + tt * 16 + l15] = acc[tt][rg];
  if (l15 == 0)
#pragma unroll
    for (int rg = 0; rg < 4; ++rg)
      Pp[(size_t)(rb + rg) * PSTR + 64] = acc[4][rg];
}

// ---------------- k4: reduce 4 slabs + normalize + ELU ----------------
__global__ __launch_bounds__(256) void k4_fin(const float* __restrict__ P,
                                              float* __restrict__ out) {
  int g = blockIdx.x * 256 + threadIdx.x;          // 524288
  int i = g >> 6, c = g & 63;
  float num = 0.f, S = 0.f;
#pragma unroll
  for (int kc = 0; kc < NSLAB; ++kc) {
    const float* p = P + (size_t)kc * NN * PSTR + (size_t)i * PSTR;
    num += p[c];
    S   += p[64];
  }
  float x = num / S;
  out[g] = x > 0.f ? x : expm1f(x);
}

extern "C" void kernel_launch(void* const* d_in, const int* in_sizes, int n_in,
                              void* d_out, int out_size, void* d_ws, size_t ws_size,
                              hipStream_t stream) {
  const float* X  = (const float*)d_in[0];   // 8192x512
  const int*   A  = (const int*)d_in[1];     // 8192x8192
  const float* W  = (const float*)d_in[2];   // 512x64
  const float* av = (const float*)d_in[3];   // 128x1
  float* out = (float*)d_out;

  char* ws = (char*)d_ws;
  unsigned short* HW = (unsigned short*)(ws + OFF_HW);
  float*          P  = (float*)(ws + OFF_P);

  k1_hw<<<NN / 16, 256, 0, stream>>>(X, W, av, HW);
  k3_gat<<<128 * NSLAB, 256, 0, stream>>>(A, HW, P);
  k4_fin<<<(size_t)NN * OF / 256, 256, 0, stream>>>(P, out);
}

// Round 2
// 397.227 us; speedup vs baseline: 1.0461x; 1.0461x over previous
//
#include <hip/hip_runtime.h>
#include <hip/hip_bf16.h>
#include <cstdint>

// ---------------- problem constants ----------------
#define NN      8192      // nodes
#define OF      64        // out features
#define KC      16        // K-chunks (k3 slabs)
#define CW      512       // K width per chunk (elements)
#define ASTR    72        // A LDS tile stride (shorts)
#define PSTR    65        // P slab row stride (floats): 64 cols + S

// ---------------- ws layout (bytes) ----------------
#define OFF_HW  0                           // HW 80x8192 u16       = 1310720
#define OFF_P   1310720                     // P16 16x8192x65 f32   = 34078720
#define OFF_WT  35389440                    // WT bf16 hi/lo packed = 131072

typedef __attribute__((ext_vector_type(8))) short  s16x8;
typedef __attribute__((ext_vector_type(4))) float  f32x4;

__device__ __forceinline__ unsigned short f2bf(float f) {
  unsigned int u = __float_as_uint(f);
  unsigned int r = (u + 0x7FFFu + ((u >> 16) & 1u)) >> 16;   // RNE
  return (unsigned short)r;
}

// ---------------- k0: pre-pack W -> bf16 hi/lo, B-frag swizzled layout ----
// Global layout per buffer: [chunk kc 0..3][col c 0..63][128 shorts], where
// short index within row = ((kg ^ (c&7))*8 + j) holds W[kc*128+kg*8+j][c].
// This is exactly the image of k1's LDS tile, so k1 stages it linearly.
__global__ __launch_bounds__(256) void k0_wt(const float* __restrict__ W,
                                             unsigned short* __restrict__ WT) {
  int t = threadIdx.x;
  int c = t & 63, part = t >> 6;            // part = chunk 0..3
  unsigned short* wh = WT;
  unsigned short* wl = WT + 4 * 64 * 128;
#pragma unroll 1
  for (int kg = 0; kg < 16; ++kg) {
    s16x8 hh, ll;
#pragma unroll
    for (int j = 0; j < 8; ++j) {
      float x = W[(size_t)(part * 128 + kg * 8 + j) * 64 + c];
      unsigned short h = f2bf(x);
      float hf = __uint_as_float(((unsigned int)h) << 16);
      hh[j] = (short)h;
      ll[j] = (short)f2bf(x - hf);
    }
    size_t o = (size_t)part * 8192 + c * 128 + ((kg ^ (c & 7)) * 8);
    *(s16x8*)(wh + o) = hh;
    *(s16x8*)(wl + o) = ll;
  }
}

// ---------------- k1: h = X @ W via bf16 MFMA, 3-term hi/lo split ---------
// h = xh@wh + xl@wh + xh@wl (residual xl@wl ~ 2^-18 rel, negligible).
// M=16 rows/block, 512 blocks, 128 threads (2 waves; wave w owns cols
// w*32..w*32+31). v_j = h_j . a_right reduced across l15 then across waves
// in LDS; e = exp(v); HW[c][j] = bf16(e_j h_j[c]), row 64 = bf16(e_j).
__global__ __launch_bounds__(128) void k1_hw(const float* __restrict__ X,
                                             const unsigned short* __restrict__ WT,
                                             const float* __restrict__ att,
                                             unsigned short* __restrict__ HW) {
  __shared__ unsigned short xh[16 * 128], xl[16 * 128];   // 4 KB each
  __shared__ unsigned short wh[64 * 128], wl[64 * 128];   // 16 KB each
  __shared__ float vbuf[2][16];

  int t = threadIdx.x;
  int lane = t & 63, w = t >> 6;
  int l15 = lane & 15, q = lane >> 4;
  int rb = blockIdx.x * 16;
  const unsigned short* WTl = WT + 4 * 64 * 128;

  f32x4 acc[2];
  acc[0] = 0.f; acc[1] = 0.f;

#pragma unroll 1
  for (int kc = 0; kc < 4; ++kc) {
    if (kc) __syncthreads();                // previous chunk's reads done

    // stage W hi/lo (linear copy of pre-swizzled global image)
#pragma unroll
    for (int i = 0; i < 8; ++i) {
      int sl = (i * 128 + t) * 8;           // short index 0..8191
      *(s16x8*)&wh[sl] = *(const s16x8*)(WT  + (size_t)kc * 8192 + sl);
      *(s16x8*)&wl[sl] = *(const s16x8*)(WTl + (size_t)kc * 8192 + sl);
    }

    // stage X chunk: 16 rows x 128 k f32 -> bf16 hi/lo, swizzled
#pragma unroll
    for (int i = 0; i < 4; ++i) {
      int lid = i * 128 + t;                // 0..511 float4 slots
      int row = lid >> 5, f4i = lid & 31;
      float4 v = ((const float4*)X)[(size_t)(rb + row) * 128 + kc * 32 + f4i];
      short4 hs, ls;
      float xv[4] = {v.x, v.y, v.z, v.w};
      short hv[4], lv[4];
#pragma unroll
      for (int j = 0; j < 4; ++j) {
        unsigned short h = f2bf(xv[j]);
        float hf = __uint_as_float(((unsigned int)h) << 16);
        hv[j] = (short)h;
        lv[j] = (short)f2bf(xv[j] - hf);
      }
      hs.x = hv[0]; hs.y = hv[1]; hs.z = hv[2]; hs.w = hv[3];
      ls.x = lv[0]; ls.y = lv[1]; ls.z = lv[2]; ls.w = lv[3];
      int kg = f4i >> 1, sub = (f4i & 1) * 4;
      int col = ((kg ^ (row & 7)) * 8) + sub;
      *(short4*)&xh[row * 128 + col] = hs;
      *(short4*)&xl[row * 128 + col] = ls;
    }
    __syncthreads();

    // MFMA: 4 k-steps x 2 col-tiles x 3 segments
#pragma unroll
    for (int ks = 0; ks < 4; ++ks) {
      int ch = ks * 4 + q;
      int acol = (ch ^ (l15 & 7)) * 8;
      s16x8 afh = *(const s16x8*)&xh[l15 * 128 + acol];
      s16x8 afl = *(const s16x8*)&xl[l15 * 128 + acol];
#pragma unroll
      for (int tti = 0; tti < 2; ++tti) {
        int c = (w * 2 + tti) * 16 + l15;
        int bcol = (ch ^ (l15 & 7)) * 8;    // c&7 == l15&7
        s16x8 bh = *(const s16x8*)&wh[c * 128 + bcol];
        s16x8 bl = *(const s16x8*)&wl[c * 128 + bcol];
        acc[tti] = __builtin_amdgcn_mfma_f32_16x16x32_bf16(afh, bh, acc[tti], 0, 0, 0);
        acc[tti] = __builtin_amdgcn_mfma_f32_16x16x32_bf16(afl, bh, acc[tti], 0, 0, 0);
        acc[tti] = __builtin_amdgcn_mfma_f32_16x16x32_bf16(afh, bl, acc[tti], 0, 0, 0);
      }
    }
  }

  // ---- v = h . a_right : reduce over this wave's 32 cols, then cross-wave
  float ar0 = att[64 + (w * 2 + 0) * 16 + l15];
  float ar1 = att[64 + (w * 2 + 1) * 16 + l15];
  float pv[4];
#pragma unroll
  for (int rg = 0; rg < 4; ++rg) {
    float v = acc[0][rg] * ar0 + acc[1][rg] * ar1;
#pragma unroll
    for (int m = 8; m > 0; m >>= 1) v += __shfl_xor(v, m, 64);
    pv[rg] = v;
  }
  if (l15 == 0) {
#pragma unroll
    for (int rg = 0; rg < 4; ++rg) vbuf[w][q * 4 + rg] = pv[rg];
  }
  __syncthreads();

  float e[4];
#pragma unroll
  for (int rg = 0; rg < 4; ++rg)
    e[rg] = expf(vbuf[0][q * 4 + rg] + vbuf[1][q * 4 + rg]);

  // ---- HW writes: C/D layout col=l15, row=q*4+rg
  int j0 = rb + q * 4;
#pragma unroll
  for (int tti = 0; tti < 2; ++tti) {
    int c = (w * 2 + tti) * 16 + l15;
#pragma unroll
    for (int rg = 0; rg < 4; ++rg)
      HW[(size_t)c * NN + j0 + rg] = f2bf(e[rg] * acc[tti][rg]);
  }
  if (w == 0 && l15 == 0) {
#pragma unroll
    for (int rg = 0; rg < 4; ++rg)
      HW[(size_t)64 * NN + j0 + rg] = f2bf(e[rg]);
  }
}

// ---------------- k3: full-depth A preload; loop has ZERO global loads -----
// (16-slab round-0 version, verbatim: block-level pipelining across 2048
// blocks is load-bearing -- round-1's CPB=4 lockstep variant exposed the
// per-chunk load latency and cost +30us.)
__global__ __launch_bounds__(256, 2) void k3_gat(const int* __restrict__ A,
                                                 const unsigned short* __restrict__ HW,
                                                 float* __restrict__ P) {
  __shared__ unsigned short bt[65 * 512];   // 66560 B, XOR-swizzled B
  __shared__ unsigned short at[64 * ASTR];  //  9216 B, per-wave A regions

  int t = threadIdx.x;
  int kc = blockIdx.x & 15;                 // XCD-affine B slice
  int mg = blockIdx.x >> 4;                 // 0..127
  int lane = t & 63, w = t >> 6;
  int l15 = lane & 15, q = lane >> 4;
  int k0 = kc * CW;
  int rowM = mg * 64;

  // A pointers: instr i covers rows w*16+i*4+q, 16 lanes x 16B contiguous
  const int* ap[4];
#pragma unroll
  for (int i = 0; i < 4; ++i)
    ap[i] = A + (size_t)(rowM + w * 16 + i * 4 + q) * NN + k0 + l15 * 4;

  // full-depth preload: all 8 steps x 4 row-groups, one 32-deep burst
  int4 av[8][4];
#pragma unroll
  for (int s = 0; s < 8; ++s)
#pragma unroll
    for (int i = 0; i < 4; ++i)
      av[s][i] = *(const int4*)(ap[i] + s * 64);

  // stage B swizzled: chunk ch of row goes to position ch ^ (row & 7)
#pragma unroll
  for (int rds = 0; rds < 16; ++rds) {
    int lid = rds * 256 + t;
    int row = lid >> 6, ch = lid & 63;
    uint4 v = *(const uint4*)(HW + (size_t)row * NN + k0 + ch * 8);
    *(uint4*)&bt[row * 512 + ((ch ^ (row & 7)) * 8)] = v;
  }
  if (t < 64) {                             // row 64 (e-row), unswizzled
    uint4 v = *(const uint4*)(HW + (size_t)64 * NN + k0 + t * 8);
    *(uint4*)&bt[64 * 512 + t * 8] = v;
  }
  __syncthreads();                          // the ONLY barrier

  // B ds_read byte-address bases (round-8-verified conflict-free)
  int swz = l15 & 7;
  int bb[4][2];
#pragma unroll
  for (int tt = 0; tt < 4; ++tt)
#pragma unroll
    for (int ks = 0; ks < 2; ++ks)
      bb[tt][ks] = ((tt * 16 + l15) * 512 + (((ks * 4 + q) ^ swz) * 8)) * 2;
  int eb0 = (64 * 512 + q * 8) * 2;
  int eb1 = (64 * 512 + (4 + q) * 8) * 2;
  int ab  = ((w * 16 + l15) * ASTR + q * 8) * 2;

  f32x4 acc[5];
#pragma unroll
  for (int tt = 0; tt < 5; ++tt) acc[tt] = 0.f;
  const s16x8 zero8 = {0, 0, 0, 0, 0, 0, 0, 0};

#pragma unroll
  for (int s = 0; s < 8; ++s) {
    // write A(s) -> wave-private tile region (cvt int{0,1} -> packed bf16)
#pragma unroll
    for (int i = 0; i < 4; ++i) {
      int4 vv = av[s][i];
      uint2 p;
      p.x = (unsigned)(vv.x | (vv.y << 16)) * 0x3F80u;
      p.y = (unsigned)(vv.z | (vv.w << 16)) * 0x3F80u;
      *(uint2*)((char*)at + (((w * 16 + i * 4 + q) * ASTR + l15 * 4) * 2)) = p;
    }

    // wave-local read-back (lgkmcnt ordering only; no s_barrier)
    s16x8 af0 = *(const s16x8*)((char*)at + ab);
    s16x8 af1 = *(const s16x8*)((char*)at + ab + 64);
    int so = s * 128;                       // step byte offset within B row
#pragma unroll
    for (int ks = 0; ks < 2; ++ks) {
      s16x8 af = ks ? af1 : af0;
#pragma unroll
      for (int tt = 0; tt < 4; ++tt) {
        s16x8 b = *(const s16x8*)((char*)bt + bb[tt][ks] + so);
        acc[tt] = __builtin_amdgcn_mfma_f32_16x16x32_bf16(af, b, acc[tt], 0, 0, 0);
      }
      s16x8 b4 = *(const s16x8*)((char*)bt + (ks ? eb1 : eb0) + so);
      b4 = (l15 == 0) ? b4 : zero8;
      acc[4] = __builtin_amdgcn_mfma_f32_16x16x32_bf16(af, b4, acc[4], 0, 0, 0);
    }
  }

  // epilogue: C/D layout col=l15, row=q*4+rg
  float* Pp = P + (size_t)kc * NN * PSTR;
  int rb = rowM + w * 16 + q * 4;
#pragma unroll
  for (int tt = 0; tt < 4; ++tt)
#pragma unroll
    for (int rg = 0; rg < 4; ++rg)
      Pp[(size_t)(rb + rg) * PSTR + tt * 16 + l15] = acc[tt][rg];
  if (l15 == 0)
#pragma unroll
    for (int rg = 0; rg < 4; ++rg)
      Pp[(size_t)(rb + rg) * PSTR + 64] = acc[4][rg];
}

// ---------------- k4: reduce 16 slabs + normalize + ELU ----------------
__global__ __launch_bounds__(256) void k4_fin(const float* __restrict__ P,
                                              float* __restrict__ out) {
  int g = blockIdx.x * 256 + threadIdx.x;          // 524288
  int i = g >> 6, c = g & 63;
  float num = 0.f, S = 0.f;
#pragma unroll
  for (int kc = 0; kc < KC; ++kc) {
    const float* p = P + (size_t)kc * NN * PSTR + (size_t)i * PSTR;
    num += p[c];
    S   += p[64];
  }
  float x = num / S;
  out[g] = x > 0.f ? x : expm1f(x);
}

extern "C" void kernel_launch(void* const* d_in, const int* in_sizes, int n_in,
                              void* d_out, int out_size, void* d_ws, size_t ws_size,
                              hipStream_t stream) {
  const float* X  = (const float*)d_in[0];   // 8192x512
  const int*   A  = (const int*)d_in[1];     // 8192x8192
  const float* W  = (const float*)d_in[2];   // 512x64
  const float* av = (const float*)d_in[3];   // 128x1
  float* out = (float*)d_out;

  char* ws = (char*)d_ws;
  unsigned short* HW = (unsigned short*)(ws + OFF_HW);
  float*          P  = (float*)(ws + OFF_P);
  unsigned short* WT = (unsigned short*)(ws + OFF_WT);

  k0_wt<<<1, 256, 0, stream>>>(W, WT);
  k1_hw<<<NN / 16, 128, 0, stream>>>(X, WT, av, HW);
  k3_gat<<<128 * KC, 256, 0, stream>>>(A, HW, P);
  k4_fin<<<(size_t)NN * OF / 256, 256, 0, stream>>>(P, out);
}

// Round 3
// 391.493 us; speedup vs baseline: 1.0614x; 1.0146x over previous
//
#include <hip/hip_runtime.h>
#include <hip/hip_bf16.h>
#include <cstdint>

// ---------------- problem constants ----------------
#define NN      8192      // nodes
#define OF      64        // out features
#define KC      16        // K-chunks
#define CW      512       // K width per chunk (elements)
#define ASTR    72        // A LDS tile stride (shorts)
#define PSTR    64        // P slab row stride (floats), 256-B aligned

// ---------------- ws layout (bytes) ----------------
#define OFF_HW  0                           // HW 80x8192 u16       = 1310720
#define OFF_P   1310720                     // P16 16x8192x64 f32   = 33554432
#define OFF_S   34865152                    // S  16x8192 f32       = 524288

typedef __attribute__((ext_vector_type(8))) short  s16x8;
typedef __attribute__((ext_vector_type(4))) float  f32x4;

__device__ __forceinline__ unsigned short f2bf(float f) {
  unsigned int u = __float_as_uint(f);
  unsigned int r = (u + 0x7FFFu + ((u >> 16) & 1u)) >> 16;   // RNE
  return (unsigned short)r;
}

// ---------------- k1: h = X @ W (LDS-tiled fp32) -> fused e/HW write -------
// (round-0 version, verbatim: issue-bound ~6-8us; MFMA rewrite was net
// slower at this tiny K -- reverted.)
__global__ __launch_bounds__(256) void k1_hw(const float* __restrict__ X,
                                             const float* __restrict__ W,
                                             const float* __restrict__ att,
                                             unsigned short* __restrict__ HW) {
  __shared__ float xs[16 * 516];
  __shared__ float ws[64 * 68];
  int t = threadIdx.x;
  int rb = blockIdx.x * 16;

  {
    const float4* src = (const float4*)(X + (size_t)rb * 512);
#pragma unroll
    for (int s = 0; s < 8; ++s) {
      int lid = s * 256 + t;
      int row = lid >> 7, kseg = lid & 127;
      *(float4*)&xs[row * 516 + kseg * 4] = src[row * 128 + kseg];
    }
  }

  int row = t >> 4, tx = t & 15;
  float4 acc = {0.f, 0.f, 0.f, 0.f};
  for (int kc = 0; kc < 8; ++kc) {
    __syncthreads();
#pragma unroll
    for (int s = 0; s < 4; ++s) {
      int lid = s * 256 + t;
      int k = lid >> 4, cs = lid & 15;
      *(float4*)&ws[k * 68 + cs * 4] =
          *(const float4*)(W + (size_t)(kc * 64 + k) * 64 + cs * 4);
    }
    __syncthreads();
#pragma unroll 16
    for (int k = 0; k < 64; ++k) {
      float x = xs[row * 516 + kc * 64 + k];
      float4 w4 = *(const float4*)&ws[k * 68 + tx * 4];
      acc.x += x * w4.x; acc.y += x * w4.y;
      acc.z += x * w4.z; acc.w += x * w4.w;
    }
  }

  float v = acc.x * att[64 + tx * 4]     + acc.y * att[64 + tx * 4 + 1] +
            acc.z * att[64 + tx * 4 + 2] + acc.w * att[64 + tx * 4 + 3];
#pragma unroll
  for (int m = 8; m > 0; m >>= 1) v += __shfl_xor(v, m, 64);
  float e = expf(v);                 // |r| <~ 21, no overflow

  int j = rb + row;
  unsigned short* hw = HW + j;
  float hv[4] = {acc.x, acc.y, acc.z, acc.w};
#pragma unroll
  for (int c = 0; c < 4; ++c)
    hw[(size_t)(tx * 4 + c) * NN] = f2bf(e * hv[c]);
  if (tx == 0) hw[(size_t)64 * NN] = f2bf(e);   // rows 65..79 never read
}

// ---------------- k3: full-depth A preload; loop has ZERO global loads -----
// (16-slab round-0 structure, verbatim except the epilogue: P rows are now
// PSTR=64 (256-B aligned) and the e-sums go to a compact S[16][8192] array
// so k4 can read float4. Block-level pipelining across 2048 blocks is
// load-bearing -- do not re-tile (round-1 lesson, +30us).)
__global__ __launch_bounds__(256, 2) void k3_gat(const int* __restrict__ A,
                                                 const unsigned short* __restrict__ HW,
                                                 float* __restrict__ P,
                                                 float* __restrict__ Sv) {
  __shared__ unsigned short bt[65 * 512];   // 66560 B, XOR-swizzled B
  __shared__ unsigned short at[64 * ASTR];  //  9216 B, per-wave A regions

  int t = threadIdx.x;
  int kc = blockIdx.x & 15;                 // XCD-affine B slice
  int mg = blockIdx.x >> 4;                 // 0..127
  int lane = t & 63, w = t >> 6;
  int l15 = lane & 15, q = lane >> 4;
  int k0 = kc * CW;
  int rowM = mg * 64;

  // A pointers: instr i covers rows w*16+i*4+q, 16 lanes x 16B contiguous
  const int* ap[4];
#pragma unroll
  for (int i = 0; i < 4; ++i)
    ap[i] = A + (size_t)(rowM + w * 16 + i * 4 + q) * NN + k0 + l15 * 4;

  // full-depth preload: all 8 steps x 4 row-groups, one 32-deep burst
  int4 av[8][4];
#pragma unroll
  for (int s = 0; s < 8; ++s)
#pragma unroll
    for (int i = 0; i < 4; ++i)
      av[s][i] = *(const int4*)(ap[i] + s * 64);

  // stage B swizzled: chunk ch of row goes to position ch ^ (row & 7)
#pragma unroll
  for (int rds = 0; rds < 16; ++rds) {
    int lid = rds * 256 + t;
    int row = lid >> 6, ch = lid & 63;
    uint4 v = *(const uint4*)(HW + (size_t)row * NN + k0 + ch * 8);
    *(uint4*)&bt[row * 512 + ((ch ^ (row & 7)) * 8)] = v;
  }
  if (t < 64) {                             // row 64 (e-row), unswizzled
    uint4 v = *(const uint4*)(HW + (size_t)64 * NN + k0 + t * 8);
    *(uint4*)&bt[64 * 512 + t * 8] = v;
  }
  __syncthreads();                          // the ONLY barrier

  // B ds_read byte-address bases (round-8-verified conflict-free)
  int swz = l15 & 7;
  int bb[4][2];
#pragma unroll
  for (int tt = 0; tt < 4; ++tt)
#pragma unroll
    for (int ks = 0; ks < 2; ++ks)
      bb[tt][ks] = ((tt * 16 + l15) * 512 + (((ks * 4 + q) ^ swz) * 8)) * 2;
  int eb0 = (64 * 512 + q * 8) * 2;
  int eb1 = (64 * 512 + (4 + q) * 8) * 2;
  int ab  = ((w * 16 + l15) * ASTR + q * 8) * 2;

  f32x4 acc[5];
#pragma unroll
  for (int tt = 0; tt < 5; ++tt) acc[tt] = 0.f;
  const s16x8 zero8 = {0, 0, 0, 0, 0, 0, 0, 0};

#pragma unroll
  for (int s = 0; s < 8; ++s) {
    // write A(s) -> wave-private tile region (cvt int{0,1} -> packed bf16)
#pragma unroll
    for (int i = 0; i < 4; ++i) {
      int4 vv = av[s][i];
      uint2 p;
      p.x = (unsigned)(vv.x | (vv.y << 16)) * 0x3F80u;
      p.y = (unsigned)(vv.z | (vv.w << 16)) * 0x3F80u;
      *(uint2*)((char*)at + (((w * 16 + i * 4 + q) * ASTR + l15 * 4) * 2)) = p;
    }

    // wave-local read-back (lgkmcnt ordering only; no s_barrier)
    s16x8 af0 = *(const s16x8*)((char*)at + ab);
    s16x8 af1 = *(const s16x8*)((char*)at + ab + 64);
    int so = s * 128;                       // step byte offset within B row
#pragma unroll
    for (int ks = 0; ks < 2; ++ks) {
      s16x8 af = ks ? af1 : af0;
#pragma unroll
      for (int tt = 0; tt < 4; ++tt) {
        s16x8 b = *(const s16x8*)((char*)bt + bb[tt][ks] + so);
        acc[tt] = __builtin_amdgcn_mfma_f32_16x16x32_bf16(af, b, acc[tt], 0, 0, 0);
      }
      s16x8 b4 = *(const s16x8*)((char*)bt + (ks ? eb1 : eb0) + so);
      b4 = (l15 == 0) ? b4 : zero8;
      acc[4] = __builtin_amdgcn_mfma_f32_16x16x32_bf16(af, b4, acc[4], 0, 0, 0);
    }
  }

  // epilogue: C/D layout col=l15, row=q*4+rg; aligned PSTR=64 + compact S
  float* Pp = P + (size_t)kc * NN * PSTR;
  int rb = rowM + w * 16 + q * 4;
#pragma unroll
  for (int tt = 0; tt < 4; ++tt)
#pragma unroll
    for (int rg = 0; rg < 4; ++rg)
      Pp[(size_t)(rb + rg) * PSTR + tt * 16 + l15] = acc[tt][rg];
  if (l15 == 0)
#pragma unroll
    for (int rg = 0; rg < 4; ++rg)
      Sv[(size_t)kc * NN + rb + rg] = acc[4][rg];
}

// ---------------- k4: reduce 16 slabs + normalize + ELU (float4) ----------
__global__ __launch_bounds__(256) void k4_fin(const float* __restrict__ P,
                                              const float* __restrict__ Sv,
                                              float* __restrict__ out) {
  int g = blockIdx.x * 256 + threadIdx.x;          // 131072 threads
  int i = g >> 4, c4 = g & 15;                     // row, float4-slot
  f32x4 num = 0.f;
  float S = 0.f;
#pragma unroll
  for (int kc = 0; kc < KC; ++kc) {
    num += *(const f32x4*)(P + (size_t)kc * NN * PSTR + (size_t)i * PSTR + c4 * 4);
    S   += Sv[(size_t)kc * NN + i];
  }
  float inv = 1.f / S;
  f32x4 x = num * inv;
  f32x4 r;
#pragma unroll
  for (int j = 0; j < 4; ++j) r[j] = x[j] > 0.f ? x[j] : expm1f(x[j]);
  *(f32x4*)(out + (size_t)i * OF + c4 * 4) = r;
}

extern "C" void kernel_launch(void* const* d_in, const int* in_sizes, int n_in,
                              void* d_out, int out_size, void* d_ws, size_t ws_size,
                              hipStream_t stream) {
  const float* X  = (const float*)d_in[0];   // 8192x512
  const int*   A  = (const int*)d_in[1];     // 8192x8192
  const float* W  = (const float*)d_in[2];   // 512x64
  const float* av = (const float*)d_in[3];   // 128x1
  float* out = (float*)d_out;

  char* ws = (char*)d_ws;
  unsigned short* HW = (unsigned short*)(ws + OFF_HW);
  float*          P  = (float*)(ws + OFF_P);
  float*          Sv = (float*)(ws + OFF_S);

  k1_hw<<<NN / 16, 256, 0, stream>>>(X, W, av, HW);
  k3_gat<<<128 * KC, 256, 0, stream>>>(A, HW, P, Sv);
  k4_fin<<<(size_t)NN * OF / 4 / 256, 256, 0, stream>>>(P, Sv, out);
}